// Round 18
// baseline (79.206 us; speedup 1.0000x reference)
//
#include <hip/hip_runtime.h>

#define Tn 256
// u = -(10*log2e)*r. x,y PRE-SCALED by log2e: dl' = log2e*dl1,
// cost_u = -6*om^2*dl' with om = 1-2^(-dl'). ALL exp2/log2 are Mitchell
// bit-tricks (full-rate VALU): 2^z = bitcast(int(fma(z,2^23,bits(1.0))))
// (saturating cvt), log2(s) = float(bits(s))*2^-23-127, -127 folded into cost.
// Validity folded into cost (invalid->CBIG). Family absmax measured: 8-16
// (threshold 145.9).
// SYMMETRY: sdtw(x,y)==sdtw(y,x) -> sim = 2*sdtw(pred,gt); (gt,pred) dropped.
// Protocol: bb double-buffered one chunk ahead; prog poll issued a chunk early
// and tested late (waitcnt hidden under compute). Final reduction FUSED via
// last-block-done atomic (counter memset per call by kernel_launch).
#define UBIG (-1.442695e9f)
#define CBIG (-3.0e9f)
#define E2(v)  __builtin_amdgcn_exp2f(v)
#define L2E 1.44269504f

// 4-wave async pipeline: wave w owns rows 64w+1..64w+64 (1 row/lane).
// Windows (mult of 32): w0 [2,290) w1 [66,386) w2 [130,450) w3 [226,514).
// Blocks 384..511 run the stats pass. Last finishing block reduces ws -> out.
__global__ __launch_bounds__(256) void sdtw_kernel(
    const float* __restrict__ pred, const float* __restrict__ gt,
    const float* __restrict__ mu, const float* __restrict__ lv,
    const float* __restrict__ ptc,
    const int* __restrict__ perm_gen, const int* __restrict__ perm_real,
    float* __restrict__ ws, int* __restrict__ cnt, float* __restrict__ out) {
  __shared__ float4 ylds4[640];        // y row (s&255), pre-scaled, padded
  __shared__ float rng[3][520];        // boundary ring: slot = diagonal d
  __shared__ volatile int prog[4];
  __shared__ float red[256];
  __shared__ float gtr_sh;

  const int t = threadIdx.x;

  if (blockIdx.x >= 384) {             // ---------- stats path ----------
    const int b = blockIdx.x - 384;

    float v = 0.0f;
    if (t < 128) {
      const float m = mu[b * 128 + t];
      const float l = lv[b * 128 + t];
      v = 1.0f + l - m * m - E2(l * L2E);
    }
    red[t] = v; __syncthreads();
    for (int s = 128; s > 0; s >>= 1) { if (t < s) red[t] += red[t + s]; __syncthreads(); }
    if (t == 0) ws[512 + b] = fmaxf(-0.5f * red[0] - 0.5f, 0.0f);
    __syncthreads();

    float g = 0.0f;
    if (t < Tn - 1)
      g = fabsf(gt[(b * Tn + t + 1) * 3 + 2] - gt[(b * Tn + t) * 3 + 2]);
    red[t] = g; __syncthreads();
    for (int s = 128; s > 0; s >>= 1) { if (t < s) red[t] += red[t + s]; __syncthreads(); }
    if (t == 0) gtr_sh = red[0];
    __syncthreads();
    const float gtr = gtr_sh;

    float p = 0.0f;
    if (t < Tn - 1) {
      const float q0 = pred[(b * Tn + t) * 3 + 2];
      const float q1 = pred[(b * Tn + t + 1) * 3 + 2];
      const float s0 = __builtin_amdgcn_rcpf(1.f + E2((q0 - 0.5f) * -14.4269504f));
      const float s1 = __builtin_amdgcn_rcpf(1.f + E2((q1 - 0.5f) * -14.4269504f));
      p = fabsf(s1 - s0);
    }
    red[t] = p; __syncthreads();
    for (int s = 128; s > 0; s >>= 1) { if (t < s) red[t] += red[t + s]; __syncthreads(); }
    if (t == 0) {
      const float pts = red[0];
      const float d1 = ptc[b] - gtr; ws[640 + b] = d1 * d1;
      const float d2 = pts - gtr;    ws[768 + b] = d2 * d2;
    }
  } else {
  // ---------- sdtw path (c0=(pred,gt), c1=d_gen, c2=d_real) ----------
  const int blk = blockIdx.x;
  const int c = blk >> 7;
  const int b = blk & 127;

  const float* x;
  const float* y;
  if (c == 0)      { x = pred + b * Tn * 3; y = gt   + b * Tn * 3; }
  else if (c == 1) { x = pred + b * Tn * 3; y = pred + perm_gen[b]  * Tn * 3; }
  else             { x = gt   + b * Tn * 3; y = gt   + perm_real[b] * Tn * 3; }

  const int w = t >> 6;
  const int lane = t & 63;
  float* rngf = (float*)&rng[0][0];

  // stage y mirror: slot s holds row (s&255), pre-scaled, 4th comp = 0
  for (int k = t; k < 640; k += 256) {
    const int row = (k & 255) * 3;
    ylds4[k] = float4{y[row] * L2E, y[row + 1] * L2E, y[row + 2] * L2E, 0.f};
  }
  for (int k = t; k < 3 * 520; k += 256) rngf[k] = UBIG;
  if (t < 4) prog[t] = 0;

  const float x0 = x[t * 3 + 0] * L2E;
  const float x1 = x[t * 3 + 1] * L2E;
  const float x2 = x[t * 3 + 2] * L2E;

  const int i = t + 1;
  const int lo = max(i + 1, 2 * i - 150);
  const int hi = min(i + Tn, 2 * i + 150);
  const unsigned span = (unsigned)(hi - lo);

  const int dstart = (w == 0) ? 2 : (w == 1) ? 66 : (w == 2) ? 130 : 226;
  const int dend   = (w == 0) ? 290 : (w == 1) ? 386 : (w == 2) ? 450 : 514;
  const bool wlt3 = (w != 3);

  __syncthreads();                     // y staged, ring init

  float lf = UBIG;
  float dgv;
  float bbA[16], bbB[16], ccA[16], ccB[16];
  int pvn = 0;

  if (w > 0) {
    // blocking startup spin (pipeline fill), then dgv + bbA + first poll
    const int need0 = dstart + 14;
    int pv = prog[w - 1];
    while (pv < need0) { __builtin_amdgcn_s_sleep(1); pv = prog[w - 1]; }
    int gb = (w - 1) * 520 + dstart - 2;
    __asm__ volatile("" : "+v"(gb) : "v"(pv));
    const float r0 = rngf[gb];                       // slot dstart-2
    dgv = (lane == 0) ? r0 : UBIG;
    #pragma unroll
    for (int k = 0; k < 16; ++k) bbA[k] = rngf[gb + 1 + k];   // slots dstart-1..+14
    pvn = prog[w - 1];                               // poll for next chunk (issued)
  } else {
    dgv = (lane == 0) ? 0.0f : UBIG;
    #pragma unroll
    for (int k = 0; k < 16; ++k) { bbA[k] = UBIG; bbB[k] = UBIG; }
  }

// cost prefetch for 16 steps of chunk at DB (validity folded; Mitchell exp2)
#define PREF16(CCX, DB) do {                                               \
    const int sb_ = (DB) - t + 254;                                        \
    const int vd_ = (DB) - lo;                                             \
    _Pragma("unroll")                                                      \
    for (int k_ = 0; k_ < 16; ++k_) {                                      \
      const float4 yv_ = ylds4[sb_ + k_];                                  \
      const float dl_ = fabsf(x0 - yv_.x) + fabsf(x1 - yv_.y) + fabsf(x2 - yv_.z); \
      const float ef_ = fmaf(dl_, -8388608.f, 1065353216.f);               \
      const float e_  = __int_as_float((int)ef_);                          \
      const float om_ = 1.f - e_;                                          \
      const float cv_ = fmaf(om_ * dl_, -6.f * om_, -127.f);               \
      CCX[k_] = ((unsigned)(vd_ + k_) <= span) ? cv_ : CBIG;               \
    } } while (0)

// 16 serial softmin steps + publish; captures res = rr[14] (d = DB+14)
#define CORE16(BBX, CCX, DB) do {                                          \
    float rr_[16];                                                         \
    _Pragma("unroll")                                                      \
    for (int k_ = 0; k_ < 16; ++k_) {                                      \
      const float upv_ = __int_as_float(__builtin_amdgcn_update_dpp(       \
          __float_as_int(BBX[k_]), __float_as_int(lf),                     \
          0x138 /*wave_shr:1*/, 0xf, 0xf, false));                         \
      float mx_, mn_;                                                      \
      __asm__("v_max3_f32 %0, %1, %2, %3" : "=v"(mx_) : "v"(upv_), "v"(lf), "v"(dgv)); \
      const float md_ = __builtin_amdgcn_fmed3f(upv_, lf, dgv);            \
      __asm__("v_min3_f32 %0, %1, %2, %3" : "=v"(mn_) : "v"(upv_), "v"(lf), "v"(dgv)); \
      const float fa_ = fmaf(md_ - mx_, 8388608.f, 1065353216.f);          \
      const float fb_ = fmaf(mn_ - mx_, 8388608.f, 1065353216.f);          \
      int ia_, ib_;                                                        \
      __asm__("v_cvt_i32_f32 %0, %1" : "=v"(ia_) : "v"(fa_));              \
      __asm__("v_cvt_i32_f32 %0, %1" : "=v"(ib_) : "v"(fb_));              \
      const float s_ = 1.0f + __int_as_float(ia_) + __int_as_float(ib_);   \
      const float fs_ = (float)__float_as_int(s_);                         \
      const float un_ = fmaf(fs_, 1.1920928955e-7f, mx_ + CCX[k_]);        \
      rr_[k_] = un_; dgv = upv_; lf = un_;                                 \
    }                                                                      \
    if (wlt3 && lane == 63) {                                              \
      _Pragma("unroll")                                                    \
      for (int k_ = 0; k_ < 16; ++k_) rngf[w * 520 + (DB) + k_] = rr_[k_]; \
      prog[w] = (DB) + 15;                                                 \
    }                                                                      \
    res = rr_[14];                                                         \
  } while (0)

// deferred-gate boundary load for chunk at DB; re-issues the poll
#define LOADBB(BBX, DB) do {                                               \
    if (w > 0) {                                                           \
      const int need_ = (DB) + 14;                                         \
      if (pvn < need_) {                                                   \
        int pv_ = prog[w - 1];                                             \
        while (pv_ < need_) { __builtin_amdgcn_s_sleep(1); pv_ = prog[w - 1]; } \
        pvn = pv_;                                                         \
      }                                                                    \
      int gb_ = (w - 1) * 520 + (DB) - 1;                                  \
      __asm__ volatile("" : "+v"(gb_) : "v"(pvn));                         \
      _Pragma("unroll")                                                    \
      for (int k_ = 0; k_ < 16; ++k_) BBX[k_] = rngf[gb_ + k_];            \
      pvn = prog[w - 1];                                                   \
    } } while (0)

  float res = UBIG;
  PREF16(ccA, dstart);
  #pragma unroll 1
  for (int db = dstart; db < dend; db += 32) {
    CORE16(bbA, ccA, db);
    LOADBB(bbB, db + 16);
    PREF16(ccB, db + 16);
    CORE16(bbB, ccB, db + 16);
    const bool more = (db + 32) < dend;
    if (more) {
      LOADBB(bbA, db + 32);
      PREF16(ccA, db + 32);
    }
  }

  // release lagging consumers (ring beyond window is UBIG-init = correct)
  if (wlt3 && lane == 63) prog[w] = 0x7fffffff;

  // d=512 value = res of w3's final chunk; r = u * -ln2/10
  if (t == 255) ws[blk] = res * -0.0693147181f;
#undef PREF16
#undef CORE16
#undef LOADBB
  }

  // ---------- last-block-done fused final reduction ----------
  __syncthreads();                       // all this block's ws stores issued
  __shared__ int is_last;
  if (t == 0) {
    __threadfence();                     // release ws stores device-wide
    const int old = atomicAdd(cnt, 1);
    is_last = (old == 511) ? 1 : 0;
  }
  __syncthreads();
  if (is_last) {
    __threadfence();                     // acquire all blocks' ws stores
    __shared__ float red2[128];
    const int offs[6] = {0, 128, 256, 512, 640, 768};
    float sums[6];
    #pragma unroll
    for (int q = 0; q < 6; ++q) {
      float v = 0.f;
      if (t < 128) v = ws[offs[q] + t];
      if (t < 128) red2[t] = v;
      __syncthreads();
      for (int s = 64; s > 0; s >>= 1) { if (t < s) red2[t] += red2[t + s]; __syncthreads(); }
      if (t == 0) sums[q] = red2[0];
      __syncthreads();
    }
    if (t == 0) {
      const float inv = 1.0f / 128.0f;
      const float sim   = 2.0f * sums[0] * inv;   // symmetry: sdtw(p,g)+sdtw(g,p)
      const float dgen  = sums[1] * inv;
      const float dreal = sums[2] * inv;
      const float nag   = sim + fabsf(dgen - dreal);
      const float kl    = sums[3] * inv;
      const float aux   = sums[4] * inv;
      const float trans = sums[5] * inv;
      out[0] = nag + kl + 0.1f * aux + 0.5f * trans;
      out[1] = nag;
      out[2] = kl;
      out[3] = aux;
      out[4] = trans;
    }
  }
}

extern "C" void kernel_launch(void* const* d_in, const int* in_sizes, int n_in,
                              void* d_out, int out_size, void* d_ws, size_t ws_size,
                              hipStream_t stream) {
  const float* pred = (const float*)d_in[0];   // (128,256,3)
  const float* gt   = (const float*)d_in[1];   // (128,256,3)
  const float* mu   = (const float*)d_in[2];   // (128,128)
  const float* lv   = (const float*)d_in[3];   // (128,128)
  const float* ptc  = (const float*)d_in[4];   // (128,1)
  const int*   pg   = (const int*)d_in[5];     // (128,)
  const int*   pr   = (const int*)d_in[6];     // (128,)
  float* ws  = (float*)d_ws;   // [0..383] sdtw, [512..639] kl, [640..767] aux, [768..895] trans
  int*   cnt = (int*)((char*)d_ws + 896 * 4);  // completion counter (4 B)
  float* out = (float*)d_out;  // 5 floats

  hipMemsetAsync(cnt, 0, 4, stream);           // reset per call (capture-legal)
  sdtw_kernel<<<512, 256, 0, stream>>>(pred, gt, mu, lv, ptc, pg, pr, ws, cnt, out);
}

// Round 19
// 78.910 us; speedup vs baseline: 1.0038x; 1.0038x over previous
//
#include <hip/hip_runtime.h>

#define Tn 256
// u = -(10*log2e)*r. x,y PRE-SCALED by log2e: dl' = log2e*dl1,
// cost_u = -6*om^2*dl' with om = 1-2^(-dl'). ALL exp2/log2 are Mitchell
// bit-tricks (full-rate VALU): 2^z = bitcast(int(fma(z,2^23,bits(1.0))))
// (saturating cvt), log2(s) = float(bits(s))*2^-23-127, -127 folded into cost.
// Validity folded into cost (invalid->CBIG). Family absmax measured: 8-16
// (threshold 145.9).
// SYMMETRY: sdtw(x,y)==sdtw(y,x) -> sim = 2*sdtw(pred,gt); (gt,pred) dropped.
// Protocol: bb double-buffered one chunk ahead; prog poll issued a chunk early
// and tested late. Final reduction FUSED via last-block-done atomic.
// SETPRIO LADDER RESTORED (R18 A/B: removing it cost +10us — producer waves
// must outrank consumer waves when 2 pipelines share a CU).
#define UBIG (-1.442695e9f)
#define CBIG (-3.0e9f)
#define E2(v)  __builtin_amdgcn_exp2f(v)
#define L2E 1.44269504f

// 4-wave async pipeline: wave w owns rows 64w+1..64w+64 (1 row/lane).
// Windows (mult of 32): w0 [2,290) w1 [66,386) w2 [130,450) w3 [226,514).
// Blocks 384..511 run the stats pass. Last finishing block reduces ws -> out.
__global__ __launch_bounds__(256) void sdtw_kernel(
    const float* __restrict__ pred, const float* __restrict__ gt,
    const float* __restrict__ mu, const float* __restrict__ lv,
    const float* __restrict__ ptc,
    const int* __restrict__ perm_gen, const int* __restrict__ perm_real,
    float* __restrict__ ws, int* __restrict__ cnt, float* __restrict__ out) {
  __shared__ float4 ylds4[640];        // y row (s&255), pre-scaled, padded
  __shared__ float rng[3][520];        // boundary ring: slot = diagonal d
  __shared__ volatile int prog[4];
  __shared__ float red[256];
  __shared__ float gtr_sh;

  const int t = threadIdx.x;

  if (blockIdx.x >= 384) {             // ---------- stats path ----------
    const int b = blockIdx.x - 384;

    float v = 0.0f;
    if (t < 128) {
      const float m = mu[b * 128 + t];
      const float l = lv[b * 128 + t];
      v = 1.0f + l - m * m - E2(l * L2E);
    }
    red[t] = v; __syncthreads();
    for (int s = 128; s > 0; s >>= 1) { if (t < s) red[t] += red[t + s]; __syncthreads(); }
    if (t == 0) ws[512 + b] = fmaxf(-0.5f * red[0] - 0.5f, 0.0f);
    __syncthreads();

    float g = 0.0f;
    if (t < Tn - 1)
      g = fabsf(gt[(b * Tn + t + 1) * 3 + 2] - gt[(b * Tn + t) * 3 + 2]);
    red[t] = g; __syncthreads();
    for (int s = 128; s > 0; s >>= 1) { if (t < s) red[t] += red[t + s]; __syncthreads(); }
    if (t == 0) gtr_sh = red[0];
    __syncthreads();
    const float gtr = gtr_sh;

    float p = 0.0f;
    if (t < Tn - 1) {
      const float q0 = pred[(b * Tn + t) * 3 + 2];
      const float q1 = pred[(b * Tn + t + 1) * 3 + 2];
      const float s0 = __builtin_amdgcn_rcpf(1.f + E2((q0 - 0.5f) * -14.4269504f));
      const float s1 = __builtin_amdgcn_rcpf(1.f + E2((q1 - 0.5f) * -14.4269504f));
      p = fabsf(s1 - s0);
    }
    red[t] = p; __syncthreads();
    for (int s = 128; s > 0; s >>= 1) { if (t < s) red[t] += red[t + s]; __syncthreads(); }
    if (t == 0) {
      const float pts = red[0];
      const float d1 = ptc[b] - gtr; ws[640 + b] = d1 * d1;
      const float d2 = pts - gtr;    ws[768 + b] = d2 * d2;
    }
  } else {
  // ---------- sdtw path (c0=(pred,gt), c1=d_gen, c2=d_real) ----------
  const int blk = blockIdx.x;
  const int c = blk >> 7;
  const int b = blk & 127;

  const float* x;
  const float* y;
  if (c == 0)      { x = pred + b * Tn * 3; y = gt   + b * Tn * 3; }
  else if (c == 1) { x = pred + b * Tn * 3; y = pred + perm_gen[b]  * Tn * 3; }
  else             { x = gt   + b * Tn * 3; y = gt   + perm_real[b] * Tn * 3; }

  const int w = t >> 6;
  const int lane = t & 63;
  float* rngf = (float*)&rng[0][0];

  // producer waves outrank consumers (R18 A/B: removing this cost +10us)
  if (w == 0)      __builtin_amdgcn_s_setprio(3);
  else if (w == 1) __builtin_amdgcn_s_setprio(2);
  else if (w == 2) __builtin_amdgcn_s_setprio(1);

  // stage y mirror: slot s holds row (s&255), pre-scaled, 4th comp = 0
  for (int k = t; k < 640; k += 256) {
    const int row = (k & 255) * 3;
    ylds4[k] = float4{y[row] * L2E, y[row + 1] * L2E, y[row + 2] * L2E, 0.f};
  }
  for (int k = t; k < 3 * 520; k += 256) rngf[k] = UBIG;
  if (t < 4) prog[t] = 0;

  const float x0 = x[t * 3 + 0] * L2E;
  const float x1 = x[t * 3 + 1] * L2E;
  const float x2 = x[t * 3 + 2] * L2E;

  const int i = t + 1;
  const int lo = max(i + 1, 2 * i - 150);
  const int hi = min(i + Tn, 2 * i + 150);
  const unsigned span = (unsigned)(hi - lo);

  const int dstart = (w == 0) ? 2 : (w == 1) ? 66 : (w == 2) ? 130 : 226;
  const int dend   = (w == 0) ? 290 : (w == 1) ? 386 : (w == 2) ? 450 : 514;
  const bool wlt3 = (w != 3);

  __syncthreads();                     // y staged, ring init

  float lf = UBIG;
  float dgv;
  float bbA[16], bbB[16], ccA[16], ccB[16];
  int pvn = 0;

  if (w > 0) {
    // blocking startup spin (pipeline fill), then dgv + bbA + first poll
    const int need0 = dstart + 14;
    int pv = prog[w - 1];
    while (pv < need0) { __builtin_amdgcn_s_sleep(1); pv = prog[w - 1]; }
    int gb = (w - 1) * 520 + dstart - 2;
    __asm__ volatile("" : "+v"(gb) : "v"(pv));
    const float r0 = rngf[gb];                       // slot dstart-2
    dgv = (lane == 0) ? r0 : UBIG;
    #pragma unroll
    for (int k = 0; k < 16; ++k) bbA[k] = rngf[gb + 1 + k];   // slots dstart-1..+14
    pvn = prog[w - 1];                               // poll for next chunk (issued)
  } else {
    dgv = (lane == 0) ? 0.0f : UBIG;
    #pragma unroll
    for (int k = 0; k < 16; ++k) { bbA[k] = UBIG; bbB[k] = UBIG; }
  }

// cost prefetch for 16 steps of chunk at DB (validity folded; Mitchell exp2)
#define PREF16(CCX, DB) do {                                               \
    const int sb_ = (DB) - t + 254;                                        \
    const int vd_ = (DB) - lo;                                             \
    _Pragma("unroll")                                                      \
    for (int k_ = 0; k_ < 16; ++k_) {                                      \
      const float4 yv_ = ylds4[sb_ + k_];                                  \
      const float dl_ = fabsf(x0 - yv_.x) + fabsf(x1 - yv_.y) + fabsf(x2 - yv_.z); \
      const float ef_ = fmaf(dl_, -8388608.f, 1065353216.f);               \
      const float e_  = __int_as_float((int)ef_);                          \
      const float om_ = 1.f - e_;                                          \
      const float cv_ = fmaf(om_ * dl_, -6.f * om_, -127.f);               \
      CCX[k_] = ((unsigned)(vd_ + k_) <= span) ? cv_ : CBIG;               \
    } } while (0)

// 16 serial softmin steps + publish; captures res = rr[14] (d = DB+14)
#define CORE16(BBX, CCX, DB) do {                                          \
    float rr_[16];                                                         \
    _Pragma("unroll")                                                      \
    for (int k_ = 0; k_ < 16; ++k_) {                                      \
      const float upv_ = __int_as_float(__builtin_amdgcn_update_dpp(       \
          __float_as_int(BBX[k_]), __float_as_int(lf),                     \
          0x138 /*wave_shr:1*/, 0xf, 0xf, false));                         \
      float mx_, mn_;                                                      \
      __asm__("v_max3_f32 %0, %1, %2, %3" : "=v"(mx_) : "v"(upv_), "v"(lf), "v"(dgv)); \
      const float md_ = __builtin_amdgcn_fmed3f(upv_, lf, dgv);            \
      __asm__("v_min3_f32 %0, %1, %2, %3" : "=v"(mn_) : "v"(upv_), "v"(lf), "v"(dgv)); \
      const float fa_ = fmaf(md_ - mx_, 8388608.f, 1065353216.f);          \
      const float fb_ = fmaf(mn_ - mx_, 8388608.f, 1065353216.f);          \
      int ia_, ib_;                                                        \
      __asm__("v_cvt_i32_f32 %0, %1" : "=v"(ia_) : "v"(fa_));              \
      __asm__("v_cvt_i32_f32 %0, %1" : "=v"(ib_) : "v"(fb_));              \
      const float s_ = 1.0f + __int_as_float(ia_) + __int_as_float(ib_);   \
      const float fs_ = (float)__float_as_int(s_);                         \
      const float un_ = fmaf(fs_, 1.1920928955e-7f, mx_ + CCX[k_]);        \
      rr_[k_] = un_; dgv = upv_; lf = un_;                                 \
    }                                                                      \
    if (wlt3 && lane == 63) {                                              \
      _Pragma("unroll")                                                    \
      for (int k_ = 0; k_ < 16; ++k_) rngf[w * 520 + (DB) + k_] = rr_[k_]; \
      prog[w] = (DB) + 15;                                                 \
    }                                                                      \
    res = rr_[14];                                                         \
  } while (0)

// deferred-gate boundary load for chunk at DB; re-issues the poll
#define LOADBB(BBX, DB) do {                                               \
    if (w > 0) {                                                           \
      const int need_ = (DB) + 14;                                         \
      if (pvn < need_) {                                                   \
        int pv_ = prog[w - 1];                                             \
        while (pv_ < need_) { __builtin_amdgcn_s_sleep(1); pv_ = prog[w - 1]; } \
        pvn = pv_;                                                         \
      }                                                                    \
      int gb_ = (w - 1) * 520 + (DB) - 1;                                  \
      __asm__ volatile("" : "+v"(gb_) : "v"(pvn));                         \
      _Pragma("unroll")                                                    \
      for (int k_ = 0; k_ < 16; ++k_) BBX[k_] = rngf[gb_ + k_];            \
      pvn = prog[w - 1];                                                   \
    } } while (0)

  float res = UBIG;
  PREF16(ccA, dstart);
  #pragma unroll 1
  for (int db = dstart; db < dend; db += 32) {
    CORE16(bbA, ccA, db);
    LOADBB(bbB, db + 16);
    PREF16(ccB, db + 16);
    CORE16(bbB, ccB, db + 16);
    const bool more = (db + 32) < dend;
    if (more) {
      LOADBB(bbA, db + 32);
      PREF16(ccA, db + 32);
    }
  }

  // release lagging consumers (ring beyond window is UBIG-init = correct)
  if (wlt3 && lane == 63) prog[w] = 0x7fffffff;

  // d=512 value = res of w3's final chunk; r = u * -ln2/10
  if (t == 255) ws[blk] = res * -0.0693147181f;
#undef PREF16
#undef CORE16
#undef LOADBB
  }

  // ---------- last-block-done fused final reduction ----------
  __builtin_amdgcn_s_setprio(0);
  __syncthreads();                       // all this block's ws stores issued
  __shared__ int is_last;
  if (t == 0) {
    __threadfence();                     // release ws stores device-wide
    const int old = atomicAdd(cnt, 1);
    is_last = (old == 511) ? 1 : 0;
  }
  __syncthreads();
  if (is_last) {
    __threadfence();                     // acquire all blocks' ws stores
    __shared__ float red2[128];
    const int offs[6] = {0, 128, 256, 512, 640, 768};
    float sums[6];
    #pragma unroll
    for (int q = 0; q < 6; ++q) {
      float v = 0.f;
      if (t < 128) v = ws[offs[q] + t];
      if (t < 128) red2[t] = v;
      __syncthreads();
      for (int s = 64; s > 0; s >>= 1) { if (t < s) red2[t] += red2[t + s]; __syncthreads(); }
      if (t == 0) sums[q] = red2[0];
      __syncthreads();
    }
    if (t == 0) {
      const float inv = 1.0f / 128.0f;
      const float sim   = 2.0f * sums[0] * inv;   // symmetry: sdtw(p,g)+sdtw(g,p)
      const float dgen  = sums[1] * inv;
      const float dreal = sums[2] * inv;
      const float nag   = sim + fabsf(dgen - dreal);
      const float kl    = sums[3] * inv;
      const float aux   = sums[4] * inv;
      const float trans = sums[5] * inv;
      out[0] = nag + kl + 0.1f * aux + 0.5f * trans;
      out[1] = nag;
      out[2] = kl;
      out[3] = aux;
      out[4] = trans;
    }
  }
}

extern "C" void kernel_launch(void* const* d_in, const int* in_sizes, int n_in,
                              void* d_out, int out_size, void* d_ws, size_t ws_size,
                              hipStream_t stream) {
  const float* pred = (const float*)d_in[0];   // (128,256,3)
  const float* gt   = (const float*)d_in[1];   // (128,256,3)
  const float* mu   = (const float*)d_in[2];   // (128,128)
  const float* lv   = (const float*)d_in[3];   // (128,128)
  const float* ptc  = (const float*)d_in[4];   // (128,1)
  const int*   pg   = (const int*)d_in[5];     // (128,)
  const int*   pr   = (const int*)d_in[6];     // (128,)
  float* ws  = (float*)d_ws;   // [0..383] sdtw, [512..639] kl, [640..767] aux, [768..895] trans
  int*   cnt = (int*)((char*)d_ws + 896 * 4);  // completion counter (4 B)
  float* out = (float*)d_out;  // 5 floats

  hipMemsetAsync(cnt, 0, 4, stream);           // reset per call (capture-legal)
  sdtw_kernel<<<512, 256, 0, stream>>>(pred, gt, mu, lv, ptc, pg, pr, ws, cnt, out);
}

// Round 20
// 70.770 us; speedup vs baseline: 1.1192x; 1.1150x over previous
//
#include <hip/hip_runtime.h>

#define Tn 256
// u = -(10*log2e)*r. x,y PRE-SCALED by log2e: dl' = log2e*dl1,
// cost_u = -6*om^2*dl' with om = 1-2^(-dl'). ALL exp2/log2 are Mitchell
// bit-tricks (full-rate VALU): 2^z = bitcast(int(fma(z,2^23,bits(1.0))))
// (saturating cvt for the softmin path), log2(s) = float(bits(s))*2^-23-127
// with the -127 folded into cost. Validity folded into cost (invalid->CBIG).
// Family absmax measured: 8 (threshold 145.9).
// SYMMETRY: sdtw(x,y)==sdtw(y,x) -> sim = 2*sdtw(pred,gt); (gt,pred) dropped.
//
// R20 = R17 verbatim. A/B history: R17 (setprio, UNFUSED final) = 66.6us
// kernel / 70.8 total; R18 (fused tail) = 77.0; R19 (fused + setprio) = 76.6.
// The fused last-block reduction's per-block __threadfence (device-scope L2
// writeback x512 blocks) cost +10us — far more than the 4us launch it saved.
#define UBIG (-1.442695e9f)
#define CBIG (-3.0e9f)
#define E2(v)  __builtin_amdgcn_exp2f(v)
#define L2E 1.44269504f

// 4-wave async pipeline: wave w owns rows 64w+1..64w+64 (1 row/lane).
// Windows (mult of 32): w0 [2,290) w1 [66,386) w2 [130,450) w3 [226,514).
// Blocks 384..511 run the stats pass.
__global__ __launch_bounds__(256) void sdtw_kernel(
    const float* __restrict__ pred, const float* __restrict__ gt,
    const float* __restrict__ mu, const float* __restrict__ lv,
    const float* __restrict__ ptc,
    const int* __restrict__ perm_gen, const int* __restrict__ perm_real,
    float* __restrict__ ws) {
  __shared__ float4 ylds4[640];        // y row (s&255), pre-scaled, padded
  __shared__ float rng[3][520];        // boundary ring: slot = diagonal d
  __shared__ volatile int prog[4];
  __shared__ float red[256];
  __shared__ float gtr_sh;

  const int t = threadIdx.x;

  if (blockIdx.x >= 384) {             // ---------- stats path ----------
    const int b = blockIdx.x - 384;

    float v = 0.0f;
    if (t < 128) {
      const float m = mu[b * 128 + t];
      const float l = lv[b * 128 + t];
      v = 1.0f + l - m * m - E2(l * L2E);
    }
    red[t] = v; __syncthreads();
    for (int s = 128; s > 0; s >>= 1) { if (t < s) red[t] += red[t + s]; __syncthreads(); }
    if (t == 0) ws[512 + b] = fmaxf(-0.5f * red[0] - 0.5f, 0.0f);
    __syncthreads();

    float g = 0.0f;
    if (t < Tn - 1)
      g = fabsf(gt[(b * Tn + t + 1) * 3 + 2] - gt[(b * Tn + t) * 3 + 2]);
    red[t] = g; __syncthreads();
    for (int s = 128; s > 0; s >>= 1) { if (t < s) red[t] += red[t + s]; __syncthreads(); }
    if (t == 0) gtr_sh = red[0];
    __syncthreads();
    const float gtr = gtr_sh;

    float p = 0.0f;
    if (t < Tn - 1) {
      const float q0 = pred[(b * Tn + t) * 3 + 2];
      const float q1 = pred[(b * Tn + t + 1) * 3 + 2];
      const float s0 = __builtin_amdgcn_rcpf(1.f + E2((q0 - 0.5f) * -14.4269504f));
      const float s1 = __builtin_amdgcn_rcpf(1.f + E2((q1 - 0.5f) * -14.4269504f));
      p = fabsf(s1 - s0);
    }
    red[t] = p; __syncthreads();
    for (int s = 128; s > 0; s >>= 1) { if (t < s) red[t] += red[t + s]; __syncthreads(); }
    if (t == 0) {
      const float pts = red[0];
      const float d1 = ptc[b] - gtr; ws[640 + b] = d1 * d1;
      const float d2 = pts - gtr;    ws[768 + b] = d2 * d2;
    }
    return;
  }

  // ---------- sdtw path (c0=(pred,gt), c1=d_gen, c2=d_real) ----------
  const int blk = blockIdx.x;
  const int c = blk >> 7;
  const int b = blk & 127;

  const float* x;
  const float* y;
  if (c == 0)      { x = pred + b * Tn * 3; y = gt   + b * Tn * 3; }
  else if (c == 1) { x = pred + b * Tn * 3; y = pred + perm_gen[b]  * Tn * 3; }
  else             { x = gt   + b * Tn * 3; y = gt   + perm_real[b] * Tn * 3; }

  const int w = t >> 6;
  const int lane = t & 63;
  float* rngf = (float*)&rng[0][0];

  // producer waves outrank consumers
  if (w == 0)      __builtin_amdgcn_s_setprio(3);
  else if (w == 1) __builtin_amdgcn_s_setprio(2);
  else if (w == 2) __builtin_amdgcn_s_setprio(1);

  // stage y mirror: slot s holds row (s&255), pre-scaled, 4th comp = 0
  for (int k = t; k < 640; k += 256) {
    const int row = (k & 255) * 3;
    ylds4[k] = float4{y[row] * L2E, y[row + 1] * L2E, y[row + 2] * L2E, 0.f};
  }
  for (int k = t; k < 3 * 520; k += 256) rngf[k] = UBIG;
  if (t < 4) prog[t] = 0;

  const float x0 = x[t * 3 + 0] * L2E;
  const float x1 = x[t * 3 + 1] * L2E;
  const float x2 = x[t * 3 + 2] * L2E;

  const int i = t + 1;
  const int lo = max(i + 1, 2 * i - 150);
  const int hi = min(i + Tn, 2 * i + 150);
  const unsigned span = (unsigned)(hi - lo);

  const int dstart = (w == 0) ? 2 : (w == 1) ? 66 : (w == 2) ? 130 : 226;
  const int dend   = (w == 0) ? 290 : (w == 1) ? 386 : (w == 2) ? 450 : 514;
  const bool wlt3 = (w != 3);

  __syncthreads();                     // y staged, ring init

  float lf = UBIG;
  float dgv;
  float bbA[16], bbB[16], ccA[16], ccB[16];
  int pvn = 0;

  if (w > 0) {
    // blocking startup spin (pipeline fill), then dgv + bbA + first poll
    const int need0 = dstart + 14;
    int pv = prog[w - 1];
    while (pv < need0) { __builtin_amdgcn_s_sleep(1); pv = prog[w - 1]; }
    int gb = (w - 1) * 520 + dstart - 2;
    __asm__ volatile("" : "+v"(gb) : "v"(pv));
    const float r0 = rngf[gb];                       // slot dstart-2
    dgv = (lane == 0) ? r0 : UBIG;
    #pragma unroll
    for (int k = 0; k < 16; ++k) bbA[k] = rngf[gb + 1 + k];   // slots dstart-1..+14
    pvn = prog[w - 1];                               // poll for next chunk (issued)
  } else {
    dgv = (lane == 0) ? 0.0f : UBIG;
    #pragma unroll
    for (int k = 0; k < 16; ++k) { bbA[k] = UBIG; bbB[k] = UBIG; }
  }

// cost prefetch for 16 steps of chunk at DB (validity folded; Mitchell exp2)
#define PREF16(CCX, DB) do {                                               \
    const int sb_ = (DB) - t + 254;                                        \
    const int vd_ = (DB) - lo;                                             \
    _Pragma("unroll")                                                      \
    for (int k_ = 0; k_ < 16; ++k_) {                                      \
      const float4 yv_ = ylds4[sb_ + k_];                                  \
      const float dl_ = fabsf(x0 - yv_.x) + fabsf(x1 - yv_.y) + fabsf(x2 - yv_.z); \
      const float ef_ = fmaf(dl_, -8388608.f, 1065353216.f);               \
      const float e_  = __int_as_float((int)ef_);                          \
      const float om_ = 1.f - e_;                                          \
      const float cv_ = fmaf(om_ * dl_, -6.f * om_, -127.f);               \
      CCX[k_] = ((unsigned)(vd_ + k_) <= span) ? cv_ : CBIG;               \
    } } while (0)

// 16 serial softmin steps + publish; captures res = rr[14] (d = DB+14)
#define CORE16(BBX, CCX, DB) do {                                          \
    float rr_[16];                                                         \
    _Pragma("unroll")                                                      \
    for (int k_ = 0; k_ < 16; ++k_) {                                      \
      const float upv_ = __int_as_float(__builtin_amdgcn_update_dpp(       \
          __float_as_int(BBX[k_]), __float_as_int(lf),                     \
          0x138 /*wave_shr:1*/, 0xf, 0xf, false));                         \
      float mx_, mn_;                                                      \
      __asm__("v_max3_f32 %0, %1, %2, %3" : "=v"(mx_) : "v"(upv_), "v"(lf), "v"(dgv)); \
      const float md_ = __builtin_amdgcn_fmed3f(upv_, lf, dgv);            \
      __asm__("v_min3_f32 %0, %1, %2, %3" : "=v"(mn_) : "v"(upv_), "v"(lf), "v"(dgv)); \
      const float fa_ = fmaf(md_ - mx_, 8388608.f, 1065353216.f);          \
      const float fb_ = fmaf(mn_ - mx_, 8388608.f, 1065353216.f);          \
      int ia_, ib_;                                                        \
      __asm__("v_cvt_i32_f32 %0, %1" : "=v"(ia_) : "v"(fa_));              \
      __asm__("v_cvt_i32_f32 %0, %1" : "=v"(ib_) : "v"(fb_));              \
      const float s_ = 1.0f + __int_as_float(ia_) + __int_as_float(ib_);   \
      const float fs_ = (float)__float_as_int(s_);                         \
      const float un_ = fmaf(fs_, 1.1920928955e-7f, mx_ + CCX[k_]);        \
      rr_[k_] = un_; dgv = upv_; lf = un_;                                 \
    }                                                                      \
    if (wlt3 && lane == 63) {                                              \
      _Pragma("unroll")                                                    \
      for (int k_ = 0; k_ < 16; ++k_) rngf[w * 520 + (DB) + k_] = rr_[k_]; \
      prog[w] = (DB) + 15;                                                 \
    }                                                                      \
    res = rr_[14];                                                         \
  } while (0)

// deferred-gate boundary load for chunk at DB; re-issues the poll
#define LOADBB(BBX, DB) do {                                               \
    if (w > 0) {                                                           \
      const int need_ = (DB) + 14;                                         \
      if (pvn < need_) {                                                   \
        int pv_ = prog[w - 1];                                             \
        while (pv_ < need_) { __builtin_amdgcn_s_sleep(1); pv_ = prog[w - 1]; } \
        pvn = pv_;                                                         \
      }                                                                    \
      int gb_ = (w - 1) * 520 + (DB) - 1;                                  \
      __asm__ volatile("" : "+v"(gb_) : "v"(pvn));                         \
      _Pragma("unroll")                                                    \
      for (int k_ = 0; k_ < 16; ++k_) BBX[k_] = rngf[gb_ + k_];            \
      pvn = prog[w - 1];                                                   \
    } } while (0)

  float res = UBIG;
  PREF16(ccA, dstart);
  #pragma unroll 1
  for (int db = dstart; db < dend; db += 32) {
    CORE16(bbA, ccA, db);
    LOADBB(bbB, db + 16);
    PREF16(ccB, db + 16);
    CORE16(bbB, ccB, db + 16);
    const bool more = (db + 32) < dend;
    if (more) {
      LOADBB(bbA, db + 32);
      PREF16(ccA, db + 32);
    }
  }

  // release lagging consumers (ring beyond window is UBIG-init = correct)
  if (wlt3 && lane == 63) prog[w] = 0x7fffffff;

  // d=512 value = res of w3's final chunk; r = u * -ln2/10
  if (t == 255) ws[blk] = res * -0.0693147181f;
#undef PREF16
#undef CORE16
#undef LOADBB
}

// Single block: reduce the 6 per-b arrays and emit (total, nag, kl, aux, trans_reg).
__global__ __launch_bounds__(128) void final_kernel(
    const float* __restrict__ ws, float* __restrict__ out) {
  const int t = threadIdx.x;
  __shared__ float red[128];
  const int offs[6] = {0, 128, 256, 512, 640, 768};
  float sums[6];
  #pragma unroll
  for (int q = 0; q < 6; ++q) {
    red[t] = ws[offs[q] + t];
    __syncthreads();
    for (int s = 64; s > 0; s >>= 1) { if (t < s) red[t] += red[t + s]; __syncthreads(); }
    if (t == 0) sums[q] = red[0];
    __syncthreads();
  }
  if (t == 0) {
    const float inv = 1.0f / 128.0f;
    const float sim   = 2.0f * sums[0] * inv;   // symmetry: sdtw(p,g)+sdtw(g,p)
    const float dgen  = sums[1] * inv;
    const float dreal = sums[2] * inv;
    const float nag   = sim + fabsf(dgen - dreal);
    const float kl    = sums[3] * inv;
    const float aux   = sums[4] * inv;
    const float trans = sums[5] * inv;
    const float total = nag + 1.0f * kl + 0.1f * aux + 0.5f * trans;
    out[0] = total;
    out[1] = nag;
    out[2] = kl;
    out[3] = aux;
    out[4] = trans;
  }
}

extern "C" void kernel_launch(void* const* d_in, const int* in_sizes, int n_in,
                              void* d_out, int out_size, void* d_ws, size_t ws_size,
                              hipStream_t stream) {
  const float* pred = (const float*)d_in[0];   // (128,256,3)
  const float* gt   = (const float*)d_in[1];   // (128,256,3)
  const float* mu   = (const float*)d_in[2];   // (128,128)
  const float* lv   = (const float*)d_in[3];   // (128,128)
  const float* ptc  = (const float*)d_in[4];   // (128,1)
  const int*   pg   = (const int*)d_in[5];     // (128,)
  const int*   pr   = (const int*)d_in[6];     // (128,)
  float* ws  = (float*)d_ws;   // [0..383] sdtw, [512..639] kl, [640..767] aux, [768..895] trans
  float* out = (float*)d_out;  // 5 floats

  sdtw_kernel<<<512, 256, 0, stream>>>(pred, gt, mu, lv, ptc, pg, pr, ws);
  final_kernel<<<1, 128, 0, stream>>>(ws, out);
}

// Round 21
// 67.177 us; speedup vs baseline: 1.1791x; 1.0535x over previous
//
#include <hip/hip_runtime.h>

#define Tn 256
// u = -(10*log2e)*r. x,y PRE-SCALED by log2e: dl' = log2e*dl1,
// cost_u = -6*om^2*dl' with om = 1-2^(-dl'). ALL exp2/log2 are Mitchell
// bit-tricks (full-rate VALU). Softmin REDUCED to 2-term:
//   u' = mx + log2(1 + 2^(md-mx)) + cost   (mn term dropped; worst-case
//   per-step error log2(3)-1 = 0.585u = 0.041r, only at 3-way ties)
// log2's -127 bias folded into cost. Validity folded into cost (CBIG).
// SYMMETRY: sdtw(x,y)==sdtw(y,x) -> sim = 2*sdtw(pred,gt); (gt,pred) dropped.
// Protocol: 32-step chunks (was 16), bb double-buffered one chunk ahead,
// prog poll issued early / tested late. Unfused final kernel (R18/19 lesson:
// fused last-block threadfence tail costs +10us).
#define UBIG (-1.442695e9f)
#define CBIG (-3.0e9f)
#define E2(v)  __builtin_amdgcn_exp2f(v)
#define L2E 1.44269504f

// 4-wave async pipeline: wave w owns rows 64w+1..64w+64 (1 row/lane).
// Windows (mult of 32): w0 [2,290) w1 [66,386) w2 [130,450) w3 [226,514).
// Blocks 384..511 run the stats pass.
__global__ __launch_bounds__(256) void sdtw_kernel(
    const float* __restrict__ pred, const float* __restrict__ gt,
    const float* __restrict__ mu, const float* __restrict__ lv,
    const float* __restrict__ ptc,
    const int* __restrict__ perm_gen, const int* __restrict__ perm_real,
    float* __restrict__ ws) {
  __shared__ float4 ylds4[640];        // y row (s&255), pre-scaled, padded
  __shared__ float rng[3][520];        // boundary ring: slot = diagonal d
  __shared__ volatile int prog[4];
  __shared__ float red[256];
  __shared__ float gtr_sh;

  const int t = threadIdx.x;

  if (blockIdx.x >= 384) {             // ---------- stats path ----------
    const int b = blockIdx.x - 384;

    float v = 0.0f;
    if (t < 128) {
      const float m = mu[b * 128 + t];
      const float l = lv[b * 128 + t];
      v = 1.0f + l - m * m - E2(l * L2E);
    }
    red[t] = v; __syncthreads();
    for (int s = 128; s > 0; s >>= 1) { if (t < s) red[t] += red[t + s]; __syncthreads(); }
    if (t == 0) ws[512 + b] = fmaxf(-0.5f * red[0] - 0.5f, 0.0f);
    __syncthreads();

    float g = 0.0f;
    if (t < Tn - 1)
      g = fabsf(gt[(b * Tn + t + 1) * 3 + 2] - gt[(b * Tn + t) * 3 + 2]);
    red[t] = g; __syncthreads();
    for (int s = 128; s > 0; s >>= 1) { if (t < s) red[t] += red[t + s]; __syncthreads(); }
    if (t == 0) gtr_sh = red[0];
    __syncthreads();
    const float gtr = gtr_sh;

    float p = 0.0f;
    if (t < Tn - 1) {
      const float q0 = pred[(b * Tn + t) * 3 + 2];
      const float q1 = pred[(b * Tn + t + 1) * 3 + 2];
      const float s0 = __builtin_amdgcn_rcpf(1.f + E2((q0 - 0.5f) * -14.4269504f));
      const float s1 = __builtin_amdgcn_rcpf(1.f + E2((q1 - 0.5f) * -14.4269504f));
      p = fabsf(s1 - s0);
    }
    red[t] = p; __syncthreads();
    for (int s = 128; s > 0; s >>= 1) { if (t < s) red[t] += red[t + s]; __syncthreads(); }
    if (t == 0) {
      const float pts = red[0];
      const float d1 = ptc[b] - gtr; ws[640 + b] = d1 * d1;
      const float d2 = pts - gtr;    ws[768 + b] = d2 * d2;
    }
    return;
  }

  // ---------- sdtw path (c0=(pred,gt), c1=d_gen, c2=d_real) ----------
  const int blk = blockIdx.x;
  const int c = blk >> 7;
  const int b = blk & 127;

  const float* x;
  const float* y;
  if (c == 0)      { x = pred + b * Tn * 3; y = gt   + b * Tn * 3; }
  else if (c == 1) { x = pred + b * Tn * 3; y = pred + perm_gen[b]  * Tn * 3; }
  else             { x = gt   + b * Tn * 3; y = gt   + perm_real[b] * Tn * 3; }

  const int w = t >> 6;
  const int lane = t & 63;
  float* rngf = (float*)&rng[0][0];

  // producer waves outrank consumers
  if (w == 0)      __builtin_amdgcn_s_setprio(3);
  else if (w == 1) __builtin_amdgcn_s_setprio(2);
  else if (w == 2) __builtin_amdgcn_s_setprio(1);

  // stage y mirror: slot s holds row (s&255), pre-scaled, 4th comp = 0
  for (int k = t; k < 640; k += 256) {
    const int row = (k & 255) * 3;
    ylds4[k] = float4{y[row] * L2E, y[row + 1] * L2E, y[row + 2] * L2E, 0.f};
  }
  for (int k = t; k < 3 * 520; k += 256) rngf[k] = UBIG;
  if (t < 4) prog[t] = 0;

  const float x0 = x[t * 3 + 0] * L2E;
  const float x1 = x[t * 3 + 1] * L2E;
  const float x2 = x[t * 3 + 2] * L2E;

  const int i = t + 1;
  const int lo = max(i + 1, 2 * i - 150);
  const int hi = min(i + Tn, 2 * i + 150);
  const unsigned span = (unsigned)(hi - lo);

  const int dstart = (w == 0) ? 2 : (w == 1) ? 66 : (w == 2) ? 130 : 226;
  const int dend   = (w == 0) ? 290 : (w == 1) ? 386 : (w == 2) ? 450 : 514;
  const bool wlt3 = (w != 3);

  __syncthreads();                     // y staged, ring init

  float lf = UBIG;
  float dgv;
  float bbA[32], bbB[32], ccA[32], ccB[32];
  int pvn = 0;

  if (w > 0) {
    // blocking startup spin (pipeline fill), then dgv + bbA + first poll
    const int need0 = dstart + 30;
    int pv = prog[w - 1];
    while (pv < need0) { __builtin_amdgcn_s_sleep(1); pv = prog[w - 1]; }
    int gb = (w - 1) * 520 + dstart - 2;
    __asm__ volatile("" : "+v"(gb) : "v"(pv));
    const float r0 = rngf[gb];                       // slot dstart-2
    dgv = (lane == 0) ? r0 : UBIG;
    #pragma unroll
    for (int k = 0; k < 32; ++k) bbA[k] = rngf[gb + 1 + k];   // slots dstart-1..+30
    pvn = prog[w - 1];                               // poll for next chunk (issued)
  } else {
    dgv = (lane == 0) ? 0.0f : UBIG;
    #pragma unroll
    for (int k = 0; k < 32; ++k) { bbA[k] = UBIG; bbB[k] = UBIG; }
  }

// cost prefetch for 32 steps of chunk at DB (validity folded; Mitchell exp2)
#define PREF32(CCX, DB) do {                                               \
    const int sb_ = (DB) - t + 254;                                        \
    const int vd_ = (DB) - lo;                                             \
    _Pragma("unroll")                                                      \
    for (int k_ = 0; k_ < 32; ++k_) {                                      \
      const float4 yv_ = ylds4[sb_ + k_];                                  \
      const float dl_ = fabsf(x0 - yv_.x) + fabsf(x1 - yv_.y) + fabsf(x2 - yv_.z); \
      const float ef_ = fmaf(dl_, -8388608.f, 1065353216.f);               \
      const float e_  = __int_as_float((int)ef_);                          \
      const float om_ = 1.f - e_;                                          \
      const float cv_ = fmaf(om_ * dl_, -6.f * om_, -127.f);               \
      CCX[k_] = ((unsigned)(vd_ + k_) <= span) ? cv_ : CBIG;               \
    } } while (0)

// 32 serial softmin steps + publish; captures res = rr[30] (d = DB+30)
#define CORE32(BBX, CCX, DB) do {                                          \
    float rr_[32];                                                         \
    _Pragma("unroll")                                                      \
    for (int k_ = 0; k_ < 32; ++k_) {                                      \
      const float upv_ = __int_as_float(__builtin_amdgcn_update_dpp(       \
          __float_as_int(BBX[k_]), __float_as_int(lf),                     \
          0x138 /*wave_shr:1*/, 0xf, 0xf, false));                         \
      float mx_;                                                           \
      __asm__("v_max3_f32 %0, %1, %2, %3" : "=v"(mx_) : "v"(upv_), "v"(lf), "v"(dgv)); \
      const float md_ = __builtin_amdgcn_fmed3f(upv_, lf, dgv);            \
      const float fa_ = fmaf(md_ - mx_, 8388608.f, 1065353216.f);          \
      int ia_;                                                             \
      __asm__("v_cvt_i32_f32 %0, %1" : "=v"(ia_) : "v"(fa_));              \
      const float s_ = 1.0f + __int_as_float(ia_);                         \
      const float fs_ = (float)__float_as_int(s_);                         \
      const float un_ = fmaf(fs_, 1.1920928955e-7f, mx_ + CCX[k_]);        \
      rr_[k_] = un_; dgv = upv_; lf = un_;                                 \
    }                                                                      \
    if (wlt3 && lane == 63) {                                              \
      _Pragma("unroll")                                                    \
      for (int k_ = 0; k_ < 32; ++k_) rngf[w * 520 + (DB) + k_] = rr_[k_]; \
      prog[w] = (DB) + 31;                                                 \
    }                                                                      \
    res = rr_[30];                                                         \
  } while (0)

// deferred-gate boundary load for chunk at DB; re-issues the poll
#define LOADBB(BBX, DB) do {                                               \
    if (w > 0) {                                                           \
      const int need_ = (DB) + 30;                                         \
      if (pvn < need_) {                                                   \
        int pv_ = prog[w - 1];                                             \
        while (pv_ < need_) { __builtin_amdgcn_s_sleep(1); pv_ = prog[w - 1]; } \
        pvn = pv_;                                                         \
      }                                                                    \
      int gb_ = (w - 1) * 520 + (DB) - 1;                                  \
      __asm__ volatile("" : "+v"(gb_) : "v"(pvn));                         \
      _Pragma("unroll")                                                    \
      for (int k_ = 0; k_ < 32; ++k_) BBX[k_] = rngf[gb_ + k_];            \
      pvn = prog[w - 1];                                                   \
    } } while (0)

  float res = UBIG;
  PREF32(ccA, dstart);
  #pragma unroll 1
  for (int db = dstart; db < dend; db += 64) {
    CORE32(bbA, ccA, db);
    if (db + 32 < dend) {
      LOADBB(bbB, db + 32);
      PREF32(ccB, db + 32);
      CORE32(bbB, ccB, db + 32);
      if (db + 64 < dend) {
        LOADBB(bbA, db + 64);
        PREF32(ccA, db + 64);
      }
    }
  }

  // release lagging consumers (ring beyond window is UBIG-init = correct)
  if (wlt3 && lane == 63) prog[w] = 0x7fffffff;

  // d=512 value = res of w3's final chunk (DB=482, k=30); r = u * -ln2/10
  if (t == 255) ws[blk] = res * -0.0693147181f;
#undef PREF32
#undef CORE32
#undef LOADBB
}

// Single block: reduce the 6 per-b arrays and emit (total, nag, kl, aux, trans_reg).
__global__ __launch_bounds__(128) void final_kernel(
    const float* __restrict__ ws, float* __restrict__ out) {
  const int t = threadIdx.x;
  __shared__ float red[128];
  const int offs[6] = {0, 128, 256, 512, 640, 768};
  float sums[6];
  #pragma unroll
  for (int q = 0; q < 6; ++q) {
    red[t] = ws[offs[q] + t];
    __syncthreads();
    for (int s = 64; s > 0; s >>= 1) { if (t < s) red[t] += red[t + s]; __syncthreads(); }
    if (t == 0) sums[q] = red[0];
    __syncthreads();
  }
  if (t == 0) {
    const float inv = 1.0f / 128.0f;
    const float sim   = 2.0f * sums[0] * inv;   // symmetry: sdtw(p,g)+sdtw(g,p)
    const float dgen  = sums[1] * inv;
    const float dreal = sums[2] * inv;
    const float nag   = sim + fabsf(dgen - dreal);
    const float kl    = sums[3] * inv;
    const float aux   = sums[4] * inv;
    const float trans = sums[5] * inv;
    const float total = nag + 1.0f * kl + 0.1f * aux + 0.5f * trans;
    out[0] = total;
    out[1] = nag;
    out[2] = kl;
    out[3] = aux;
    out[4] = trans;
  }
}

extern "C" void kernel_launch(void* const* d_in, const int* in_sizes, int n_in,
                              void* d_out, int out_size, void* d_ws, size_t ws_size,
                              hipStream_t stream) {
  const float* pred = (const float*)d_in[0];   // (128,256,3)
  const float* gt   = (const float*)d_in[1];   // (128,256,3)
  const float* mu   = (const float*)d_in[2];   // (128,128)
  const float* lv   = (const float*)d_in[3];   // (128,128)
  const float* ptc  = (const float*)d_in[4];   // (128,1)
  const int*   pg   = (const int*)d_in[5];     // (128,)
  const int*   pr   = (const int*)d_in[6];     // (128,)
  float* ws  = (float*)d_ws;   // [0..383] sdtw, [512..639] kl, [640..767] aux, [768..895] trans
  float* out = (float*)d_out;  // 5 floats

  sdtw_kernel<<<512, 256, 0, stream>>>(pred, gt, mu, lv, ptc, pg, pr, ws);
  final_kernel<<<1, 128, 0, stream>>>(ws, out);
}